// Round 2
// baseline (1876.740 us; speedup 1.0000x reference)
//
#include <hip/hip_runtime.h>
#include <math.h>

// (B,C,F,T) = (4,64,256,256), DC=16
#define NB 4
#define NC 64
#define NF 256
#define NT 256
#define PLANE   65536
#define BSTRIDE 4194304

// ---- workspace layout (BYTE offsets), total 58,851,328 B = 56.1 MB ----
constexpr size_t WT_B  = 0;          // float[5120]   64x80 conv weights (transposed)
constexpr size_t CP_B  = 20480;      // float[240]    80 x {inv,beta,alpha}
constexpr size_t WPS_B = 21504;      // float[1024]   64x16  wp*inv
constexpr size_t BA_B  = 25600;      // float[128]    64 x {beta,alpha}
constexpr size_t W2T_B = 26112;      // float[24576]  384x64 w2 transposed
constexpr size_t QT_B  = 131072;     // bf16[4194304] (B,F,T,16)
constexpr size_t KT_B  = 8519680;    // bf16          (B,F,T,16)
constexpr size_t FO_B  = 16908288;   // bf16          (B,F,T,16)
constexpr size_t QF_B  = 25296896;   // bf16          (B,T,F,16)
constexpr size_t KF_B  = 33685504;   // bf16          (B,T,F,16)
constexpr size_t V_B   = 42074112;   // bf16          (B,T,F,16)
constexpr size_t Y_B   = 25296896;   // bf16[16777216] y_tfsa, overlaps QF/KF/V (dead by then)

__device__ __forceinline__ unsigned f2b(float f) {
  unsigned u = __builtin_bit_cast(unsigned, f);
  return (u + 0x7fffu + ((u >> 16) & 1u)) >> 16;          // RNE
}
__device__ __forceinline__ float blo(unsigned u) { return __builtin_bit_cast(float, u << 16); }
__device__ __forceinline__ float bhi(unsigned u) { return __builtin_bit_cast(float, u & 0xffff0000u); }
__device__ __forceinline__ uint4 pack8(const float* s) {
  uint4 r;
  r.x = f2b(s[0]) | (f2b(s[1]) << 16);
  r.y = f2b(s[2]) | (f2b(s[3]) << 16);
  r.z = f2b(s[4]) | (f2b(s[5]) << 16);
  r.w = f2b(s[6]) | (f2b(s[7]) << 16);
  return r;
}

// ---------------- setup: folded BN params + weight transposes ----------------
__global__ __launch_bounds__(256) void setup_k(
    const float* __restrict__ wf, const float* __restrict__ fg, const float* __restrict__ fb,
    const float* __restrict__ fm, const float* __restrict__ fv, const float* __restrict__ fa,
    const float* __restrict__ wt, const float* __restrict__ tg, const float* __restrict__ tb,
    const float* __restrict__ tm, const float* __restrict__ tv, const float* __restrict__ ta,
    const float* __restrict__ wp, const float* __restrict__ pg, const float* __restrict__ pb,
    const float* __restrict__ pm, const float* __restrict__ pv, const float* __restrict__ pa,
    const float* __restrict__ w2, float* __restrict__ wsf)
{
  char* ws = (char*)wsf;
  int tid  = blockIdx.x * blockDim.x + threadIdx.x;
  int nthr = gridDim.x * blockDim.x;
  float* WT  = (float*)(ws + WT_B);
  float* cp  = (float*)(ws + CP_B);
  float* wps = (float*)(ws + WPS_B);
  float* ba  = (float*)(ws + BA_B);
  float* w2T = (float*)(ws + W2T_B);
  for (int i = tid; i < 64*80; i += nthr) {
    int c = i / 80, o = i % 80;
    WT[i] = (o < 48) ? wf[o*64 + c] : wt[(o-48)*64 + c];
  }
  for (int o = tid; o < 80; o += nthr) {
    float g, bb, m, v, a;
    if (o < 48) { g = fg[o]; bb = fb[o]; m = fm[o]; v = fv[o]; a = fa[o]; }
    else { int j = o - 48; g = tg[j]; bb = tb[j]; m = tm[j]; v = tv[j]; a = ta[j]; }
    float inv = g * rsqrtf(v + 1e-5f);
    cp[o*3+0] = inv; cp[o*3+1] = bb - m*inv; cp[o*3+2] = a;
  }
  for (int i = tid; i < 1024; i += nthr) {
    int o = i >> 4;
    float inv = pg[o] * rsqrtf(pv[o] + 1e-5f);
    wps[i] = wp[i] * inv;
  }
  for (int o = tid; o < 64; o += nthr) {
    float inv = pg[o] * rsqrtf(pv[o] + 1e-5f);
    ba[o*2+0] = pb[o] - pm[o]*inv; ba[o*2+1] = pa[o];
  }
  for (int i = tid; i < 384*64; i += nthr) {
    int og = i >> 6, c = i & 63;
    w2T[i] = w2[c*384 + og];
  }
}

// -------- fused conv1x1(wf|wt) + BN + PReLU, deinterleave, store bf16 --------
__global__ __launch_bounds__(256) void conv_qkv_k(const float* __restrict__ x, float* wsf)
{
  char* ws = (char*)wsf;
  const int b = blockIdx.x >> 8;
  const int f = blockIdx.x & 255;
  const int t = threadIdx.x;
  const float* WT = (const float*)(ws + WT_B);   // wave-uniform rows -> s_load
  const float* cp = (const float*)(ws + CP_B);
  const float* xb = x + (size_t)b*BSTRIDE + (size_t)f*NT + t;
  float acc[80];
#pragma unroll
  for (int o = 0; o < 80; ++o) acc[o] = 0.f;
  for (int c = 0; c < 64; ++c) {
    float xc = xb[(size_t)c*PLANE];
    const float* w = WT + c*80;
#pragma unroll
    for (int o = 0; o < 80; ++o) acc[o] += w[o]*xc;
  }
  float q[16], k[16], v[16], qt[16], kt[16];
#pragma unroll
  for (int j = 0; j < 16; ++j) {
    { int ch = 3*j;      float z = acc[ch]*cp[ch*3]+cp[ch*3+1]; q[j]  = z<0.f ? cp[ch*3+2]*z : z; }
    { int ch = 3*j+1;    float z = acc[ch]*cp[ch*3]+cp[ch*3+1]; k[j]  = z<0.f ? cp[ch*3+2]*z : z; }
    { int ch = 3*j+2;    float z = acc[ch]*cp[ch*3]+cp[ch*3+1]; v[j]  = z<0.f ? cp[ch*3+2]*z : z; }
    { int ch = 48+2*j;   float z = acc[ch]*cp[ch*3]+cp[ch*3+1]; qt[j] = z<0.f ? cp[ch*3+2]*z : z; }
    { int ch = 48+2*j+1; float z = acc[ch]*cp[ch*3]+cp[ch*3+1]; kt[j] = z<0.f ? cp[ch*3+2]*z : z; }
  }
  size_t fo = (((size_t)b*NT + t)*NF + f)*16;   // (B,T,F,16) elements
  size_t to = (((size_t)b*NF + f)*NT + t)*16;   // (B,F,T,16) elements
  uint4* Qf = (uint4*)((unsigned short*)(ws + QF_B) + fo);
  uint4* Kf = (uint4*)((unsigned short*)(ws + KF_B) + fo);
  uint4* Vv = (uint4*)((unsigned short*)(ws + V_B)  + fo);
  uint4* Qt = (uint4*)((unsigned short*)(ws + QT_B) + to);
  uint4* Kt = (uint4*)((unsigned short*)(ws + KT_B) + to);
  Qf[0] = pack8(q);    Qf[1] = pack8(q+8);
  Kf[0] = pack8(k);    Kf[1] = pack8(k+8);
  Vv[0] = pack8(v);    Vv[1] = pack8(v+8);
  Qt[0] = pack8(qt);   Qt[1] = pack8(qt+8);
  Kt[0] = pack8(kt);   Kt[1] = pack8(kt+8);
}

// -------------------- f-attention: per (b,t), 32-row S tiles --------------------
__global__ __launch_bounds__(256) void fattn_k(float* wsf)
{
  __shared__ float    S[32*257];     // 32.9 KB
  __shared__ unsigned Vsb[256*8];    // 8 KB  (V rows, raw bf16 pairs)
  __shared__ float    red[256];
  __shared__ float    rinvs[32];
  char* ws = (char*)wsf;
  const int b = blockIdx.x >> 8;
  const int t = blockIdx.x & 255;
  const int tid = threadIdx.x;
  const size_t base = (((size_t)b*NT + t)*NF)*16;
  const unsigned short* Qh = (const unsigned short*)(ws + QF_B) + base;
  const unsigned short* Kh = (const unsigned short*)(ws + KF_B) + base;
  const uint4* Vb4 = (const uint4*)((const unsigned short*)(ws + V_B) + base);
  unsigned short* Foh = (unsigned short*)(ws + FO_B);
  ((uint4*)Vsb)[tid*2]   = Vb4[tid*2];
  ((uint4*)Vsb)[tid*2+1] = Vb4[tid*2+1];
  float kr[16];
  {
    const uint4* Kb4 = (const uint4*)(Kh + (size_t)tid*16);
    uint4 k0 = Kb4[0], k1 = Kb4[1];
    unsigned kw[8] = {k0.x,k0.y,k0.z,k0.w,k1.x,k1.y,k1.z,k1.w};
#pragma unroll
    for (int j = 0; j < 8; ++j) { kr[2*j] = blo(kw[j]); kr[2*j+1] = bhi(kw[j]); }
  }
  __syncthreads();
  const int r = tid & 31, p = tid >> 5;
  const int prow = tid >> 3, q = tid & 7;
  for (int fb = 0; fb < 8; ++fb) {
    const int f0 = fb*32;
#pragma unroll 4
    for (int fr = 0; fr < 32; ++fr) {
      const unsigned* qw = (const unsigned*)(Qh + (size_t)(f0+fr)*16); // uniform -> s_load
      float s = 0.f;
#pragma unroll
      for (int j = 0; j < 8; ++j) {
        unsigned w = qw[j];
        s += blo(w)*kr[2*j] + bhi(w)*kr[2*j+1];
      }
      S[fr*257 + tid] = s*0.25f;
    }
    __syncthreads();
    float* Srow = S + r*257 + p*32;
    float m = -3.4e38f;
#pragma unroll
    for (int i = 0; i < 32; ++i) m = fmaxf(m, Srow[i]);
    red[tid] = m;
    __syncthreads();
    m = red[r];
#pragma unroll
    for (int k = 1; k < 8; ++k) m = fmaxf(m, red[32*k + r]);
    __syncthreads();
    float sum = 0.f;
#pragma unroll
    for (int i = 0; i < 32; ++i) { float e = __expf(Srow[i]-m); Srow[i] = e; sum += e; }
    red[tid] = sum;
    __syncthreads();
    if (tid < 32) {
      float s2 = red[tid];
#pragma unroll
      for (int k = 1; k < 8; ++k) s2 += red[32*k + tid];
      rinvs[tid] = 1.f / s2;
    }
    __syncthreads();
    const float* Sr = S + prow*257;
    float a0 = 0.f, a1 = 0.f;
#pragma unroll 8
    for (int y = 0; y < 256; ++y) {
      float pw = Sr[y];                       // 8-way broadcast
      unsigned pv = Vsb[y*8 + q];
      a0 += pw*blo(pv); a1 += pw*bhi(pv);
    }
    float ri = rinvs[prow];
    size_t off = (((size_t)b*NF + (f0+prow))*NT + t)*16 + q*2;
    *(unsigned*)(Foh + off) = f2b(a0*ri) | (f2b(a1*ri) << 16);
    __syncthreads();
  }
}

// ---- t-attention (causal) + fused wp conv + BN + PReLU + residual -> Y bf16 ----
__global__ __launch_bounds__(256) void tattn_k(const float* __restrict__ x, float* wsf)
{
  __shared__ float    S[32*257];
  __shared__ unsigned Fsb[256*8];
  __shared__ float    red[256];
  __shared__ float    rinvs[32];
  __shared__ float    Touts[32*17];
  __shared__ float    wpl[1024];
  __shared__ float    bal[128];
  char* ws = (char*)wsf;
  const int b = blockIdx.x >> 8;
  const int f = blockIdx.x & 255;
  const int tid = threadIdx.x;
  const size_t base = (((size_t)b*NF + f)*NT)*16;
  const unsigned short* Qh = (const unsigned short*)(ws + QT_B) + base;
  const unsigned short* Kh = (const unsigned short*)(ws + KT_B) + base;
  const uint4* Fb4 = (const uint4*)((const unsigned short*)(ws + FO_B) + base);
  unsigned short* Yh = (unsigned short*)(ws + Y_B);
  ((uint4*)Fsb)[tid*2]   = Fb4[tid*2];
  ((uint4*)Fsb)[tid*2+1] = Fb4[tid*2+1];
  ((float4*)wpl)[tid] = ((const float4*)(ws + WPS_B))[tid];
  if (tid < 32) ((float4*)bal)[tid] = ((const float4*)(ws + BA_B))[tid];
  float kr[16];
  {
    const uint4* Kb4 = (const uint4*)(Kh + (size_t)tid*16);
    uint4 k0 = Kb4[0], k1 = Kb4[1];
    unsigned kw[8] = {k0.x,k0.y,k0.z,k0.w,k1.x,k1.y,k1.z,k1.w};
#pragma unroll
    for (int j = 0; j < 8; ++j) { kr[2*j] = blo(kw[j]); kr[2*j+1] = bhi(kw[j]); }
  }
  __syncthreads();
  const int r = tid & 31, p = tid >> 5;
  const int prow = tid >> 3, q = tid & 7;
  const int tl = tid & 31, ogrp = tid >> 5;
  for (int tb = 0; tb < 8; ++tb) {
    const int t0 = tb*32;
#pragma unroll 4
    for (int fr = 0; fr < 32; ++fr) {
      const int tq = t0 + fr;
      const unsigned* qw = (const unsigned*)(Qh + (size_t)tq*16);
      float s = 0.f;
#pragma unroll
      for (int j = 0; j < 8; ++j) {
        unsigned w = qw[j];
        s += blo(w)*kr[2*j] + bhi(w)*kr[2*j+1];
      }
      s *= 0.25f;
      if (tid > tq) s = -3.4e38f;            // causal
      S[fr*257 + tid] = s;
    }
    __syncthreads();
    float* Srow = S + r*257 + p*32;
    float m = -3.4e38f;
#pragma unroll
    for (int i = 0; i < 32; ++i) m = fmaxf(m, Srow[i]);
    red[tid] = m;
    __syncthreads();
    m = red[r];
#pragma unroll
    for (int k = 1; k < 8; ++k) m = fmaxf(m, red[32*k + r]);
    __syncthreads();
    float sum = 0.f;
#pragma unroll
    for (int i = 0; i < 32; ++i) { float e = __expf(Srow[i]-m); Srow[i] = e; sum += e; }
    red[tid] = sum;
    __syncthreads();
    if (tid < 32) {
      float s2 = red[tid];
#pragma unroll
      for (int k = 1; k < 8; ++k) s2 += red[32*k + tid];
      rinvs[tid] = 1.f / s2;
    }
    __syncthreads();
    const float* Sr = S + prow*257;
    float a0 = 0.f, a1 = 0.f;
#pragma unroll 8
    for (int y = 0; y < 256; ++y) {
      float pw = Sr[y];
      unsigned pv = Fsb[y*8 + q];
      a0 += pw*blo(pv); a1 += pw*bhi(pv);
    }
    float ri = rinvs[prow];
    Touts[prow*17 + 2*q]     = a0*ri;
    Touts[prow*17 + 2*q + 1] = a1*ri;
    __syncthreads();
    // epilogue: Y[b][o][f][t0+tl] = prelu(bn(wp @ Tout[tl])) + x, stored bf16
    float tr[16];
#pragma unroll
    for (int c = 0; c < 16; ++c) tr[c] = Touts[tl*17 + c];
    const int tg = t0 + tl;
#pragma unroll
    for (int kk = 0; kk < 8; ++kk) {
      const int o = ogrp*8 + kk;
      const float* wr = wpl + o*16;
      float z = 0.f;
#pragma unroll
      for (int c = 0; c < 16; ++c) z += wr[c]*tr[c];
      z += bal[o*2];
      z = z < 0.f ? bal[o*2+1]*z : z;
      size_t oa = (((size_t)b*NC + o)*NF + f)*NT + tg;
      Yh[oa] = (unsigned short)f2b(z + x[oa]);
    }
    __syncthreads();
  }
}

// ---- LN (contiguous 64-groups) + MLP 64->384->gelu->64 + gamma + residual ----
__global__ __launch_bounds__(256) void mlp_k(
    const float* __restrict__ x, const float* __restrict__ lnw, const float* __restrict__ lnb,
    const float* __restrict__ w1, const float* __restrict__ b1,
    const float* __restrict__ b2, const float* __restrict__ gamma,
    const float* wsf, float* __restrict__ out)
{
  const char* ws = (const char*)wsf;
  const int row = blockIdx.x*256 + threadIdx.x;
  const int b  = row >> 16;
  const int rr = row & 65535;
  const uint4* Yb4 = (const uint4*)((const unsigned short*)(ws + Y_B)
                                    + ((size_t)b*BSTRIDE + (size_t)rr*64));
  const float* w2T = (const float*)(ws + W2T_B);
  float yv[64];
#pragma unroll
  for (int j = 0; j < 8; ++j) {
    uint4 u = Yb4[j];
    unsigned ww[4] = {u.x, u.y, u.z, u.w};
#pragma unroll
    for (int k2 = 0; k2 < 4; ++k2) {
      yv[j*8 + 2*k2]     = blo(ww[k2]);
      yv[j*8 + 2*k2 + 1] = bhi(ww[k2]);
    }
  }
  float mu = 0.f;
#pragma unroll
  for (int c = 0; c < 64; ++c) mu += yv[c];
  mu *= (1.f/64.f);
  float var = 0.f;
#pragma unroll
  for (int c = 0; c < 64; ++c) { float d = yv[c]-mu; var += d*d; }
  var *= (1.f/64.f);
  const float sc = rsqrtf(var + 1e-6f);
#pragma unroll
  for (int c = 0; c < 64; ++c) yv[c] = (yv[c]-mu)*sc*lnw[c] + lnb[c];
  float o64[64];
#pragma unroll
  for (int c = 0; c < 64; ++c) o64[c] = 0.f;
  for (int g = 0; g < 384; ++g) {
    const float* w1r = w1 + g*64;            // uniform -> s_load
    float h0=0.f,h1=0.f,h2=0.f,h3=0.f;
#pragma unroll
    for (int c = 0; c < 64; c += 4) {
      h0 += w1r[c+0]*yv[c+0];
      h1 += w1r[c+1]*yv[c+1];
      h2 += w1r[c+2]*yv[c+2];
      h3 += w1r[c+3]*yv[c+3];
    }
    float h = ((h0+h1)+(h2+h3)) + b1[g];
    h = 0.5f*h*(1.f + erff(h*0.70710678118654752f));
    const float* w2r = w2T + g*64;
#pragma unroll
    for (int c = 0; c < 64; ++c) o64[c] += w2r[c]*h;
  }
  const size_t obase = (size_t)b*BSTRIDE + rr;
#pragma unroll 4
  for (int c = 0; c < 64; ++c) {
    float val = gamma[c]*(o64[c] + b2[c]);
    size_t a2 = obase + (size_t)c*PLANE;
    out[a2] = x[a2] + val;
  }
}

extern "C" void kernel_launch(void* const* d_in, const int* in_sizes, int n_in,
                              void* d_out, int out_size, void* d_ws, size_t ws_size,
                              hipStream_t stream) {
  const float* x    = (const float*)d_in[0];
  const float* wf   = (const float*)d_in[1];
  const float* f_g  = (const float*)d_in[2];
  const float* f_b  = (const float*)d_in[3];
  const float* f_m  = (const float*)d_in[4];
  const float* f_v  = (const float*)d_in[5];
  const float* f_a  = (const float*)d_in[6];
  const float* wt   = (const float*)d_in[7];
  const float* t_g  = (const float*)d_in[8];
  const float* t_b  = (const float*)d_in[9];
  const float* t_m  = (const float*)d_in[10];
  const float* t_v  = (const float*)d_in[11];
  const float* t_a  = (const float*)d_in[12];
  const float* wp   = (const float*)d_in[13];
  const float* p_g  = (const float*)d_in[14];
  const float* p_b  = (const float*)d_in[15];
  const float* p_m  = (const float*)d_in[16];
  const float* p_v  = (const float*)d_in[17];
  const float* p_a  = (const float*)d_in[18];
  const float* ln_w = (const float*)d_in[19];
  const float* ln_b = (const float*)d_in[20];
  const float* w1   = (const float*)d_in[21];
  const float* b1   = (const float*)d_in[22];
  const float* w2   = (const float*)d_in[23];
  const float* b2   = (const float*)d_in[24];
  const float* gm   = (const float*)d_in[25];
  float* ws  = (float*)d_ws;
  float* out = (float*)d_out;

  setup_k<<<96, 256, 0, stream>>>(wf, f_g, f_b, f_m, f_v, f_a,
                                  wt, t_g, t_b, t_m, t_v, t_a,
                                  wp, p_g, p_b, p_m, p_v, p_a, w2, ws);
  conv_qkv_k<<<NB*NF, 256, 0, stream>>>(x, ws);
  fattn_k   <<<NB*NT, 256, 0, stream>>>(ws);
  tattn_k   <<<NB*NF, 256, 0, stream>>>(x, ws);
  mlp_k     <<<1024,  256, 0, stream>>>(x, ln_w, ln_b, w1, b1, b2, gm, ws, out);
}

// Round 3
// 757.285 us; speedup vs baseline: 2.4782x; 2.4782x over previous
//
#include <hip/hip_runtime.h>
#include <math.h>

// (B,C,F,T) = (4,64,256,256), DC=16
#define NB 4
#define NC 64
#define NF 256
#define NT 256
#define PLANE   65536
#define BSTRIDE 4194304

// ---- workspace layout (BYTE offsets), total 58,851,328 B = 56.1 MB ----
constexpr size_t WT_B   = 0;          // float[5120]   64x80 conv weights (transposed)
constexpr size_t CP_B   = 20480;      // float[240]    80 x {inv,beta,alpha}
constexpr size_t WPS_B  = 21504;      // float[1024]   64x16  wp*inv
constexpr size_t BA_B   = 25600;      // float[128]    64 x {beta,alpha}
constexpr size_t W1BF_B = 26112;      // u16[24576]    w1 bf16 (384x64) row-major
constexpr size_t W2BF_B = 75264;      // u16[24576]    w2 bf16 (64x384) row-major
constexpr size_t QT_B   = 131072;     // bf16[4194304] (B,F,T,16)
constexpr size_t KT_B   = 8519680;    // bf16          (B,F,T,16)
constexpr size_t FO_B   = 16908288;   // bf16          (B,F,T,16)
constexpr size_t QF_B   = 25296896;   // bf16          (B,T,F,16)
constexpr size_t KF_B   = 33685504;   // bf16          (B,T,F,16)
constexpr size_t V_B    = 42074112;   // bf16          (B,T,F,16)
constexpr size_t Y_B    = 25296896;   // bf16[16777216] y_tfsa, overlaps QF/KF/V (dead by then)

typedef __bf16 bf16x8 __attribute__((ext_vector_type(8)));
typedef float  f32x4  __attribute__((ext_vector_type(4)));

__device__ __forceinline__ unsigned f2b(float f) {
  unsigned u = __builtin_bit_cast(unsigned, f);
  return (u + 0x7fffu + ((u >> 16) & 1u)) >> 16;          // RNE
}
__device__ __forceinline__ float blo(unsigned u) { return __builtin_bit_cast(float, u << 16); }
__device__ __forceinline__ float bhi(unsigned u) { return __builtin_bit_cast(float, u & 0xffff0000u); }
__device__ __forceinline__ uint4 pack8(const float* s) {
  uint4 r;
  r.x = f2b(s[0]) | (f2b(s[1]) << 16);
  r.y = f2b(s[2]) | (f2b(s[3]) << 16);
  r.z = f2b(s[4]) | (f2b(s[5]) << 16);
  r.w = f2b(s[6]) | (f2b(s[7]) << 16);
  return r;
}

// ---------------- setup: folded BN params + weight transposes ----------------
__global__ __launch_bounds__(256) void setup_k(
    const float* __restrict__ wf, const float* __restrict__ fg, const float* __restrict__ fb,
    const float* __restrict__ fm, const float* __restrict__ fv, const float* __restrict__ fa,
    const float* __restrict__ wt, const float* __restrict__ tg, const float* __restrict__ tb,
    const float* __restrict__ tm, const float* __restrict__ tv, const float* __restrict__ ta,
    const float* __restrict__ wp, const float* __restrict__ pg, const float* __restrict__ pb,
    const float* __restrict__ pm, const float* __restrict__ pv, const float* __restrict__ pa,
    const float* __restrict__ w1, const float* __restrict__ w2, float* __restrict__ wsf)
{
  char* ws = (char*)wsf;
  int tid  = blockIdx.x * blockDim.x + threadIdx.x;
  int nthr = gridDim.x * blockDim.x;
  float* WT  = (float*)(ws + WT_B);
  float* cp  = (float*)(ws + CP_B);
  float* wps = (float*)(ws + WPS_B);
  float* ba  = (float*)(ws + BA_B);
  unsigned short* w1b = (unsigned short*)(ws + W1BF_B);
  unsigned short* w2b = (unsigned short*)(ws + W2BF_B);
  for (int i = tid; i < 64*80; i += nthr) {
    int c = i / 80, o = i % 80;
    WT[i] = (o < 48) ? wf[o*64 + c] : wt[(o-48)*64 + c];
  }
  for (int o = tid; o < 80; o += nthr) {
    float g, bb, m, v, a;
    if (o < 48) { g = fg[o]; bb = fb[o]; m = fm[o]; v = fv[o]; a = fa[o]; }
    else { int j = o - 48; g = tg[j]; bb = tb[j]; m = tm[j]; v = tv[j]; a = ta[j]; }
    float inv = g * rsqrtf(v + 1e-5f);
    cp[o*3+0] = inv; cp[o*3+1] = bb - m*inv; cp[o*3+2] = a;
  }
  for (int i = tid; i < 1024; i += nthr) {
    int o = i >> 4;
    float inv = pg[o] * rsqrtf(pv[o] + 1e-5f);
    wps[i] = wp[i] * inv;
  }
  for (int o = tid; o < 64; o += nthr) {
    float inv = pg[o] * rsqrtf(pv[o] + 1e-5f);
    ba[o*2+0] = pb[o] - pm[o]*inv; ba[o*2+1] = pa[o];
  }
  for (int i = tid; i < 384*64; i += nthr) {
    w1b[i] = (unsigned short)f2b(w1[i]);   // w1b[g][c], 384x64
    w2b[i] = (unsigned short)f2b(w2[i]);   // w2b[c][g], 64x384
  }
}

// -------- fused conv1x1(wf|wt) + BN + PReLU, deinterleave, store bf16 --------
__global__ __launch_bounds__(256) void conv_qkv_k(const float* __restrict__ x, float* wsf)
{
  char* ws = (char*)wsf;
  const int b = blockIdx.x >> 8;
  const int f = blockIdx.x & 255;
  const int t = threadIdx.x;
  const float* WT = (const float*)(ws + WT_B);   // wave-uniform rows -> s_load
  const float* cp = (const float*)(ws + CP_B);
  const float* xb = x + (size_t)b*BSTRIDE + (size_t)f*NT + t;
  float acc[80];
#pragma unroll
  for (int o = 0; o < 80; ++o) acc[o] = 0.f;
  for (int c = 0; c < 64; ++c) {
    float xc = xb[(size_t)c*PLANE];
    const float* w = WT + c*80;
#pragma unroll
    for (int o = 0; o < 80; ++o) acc[o] += w[o]*xc;
  }
  float q[16], k[16], v[16], qt[16], kt[16];
#pragma unroll
  for (int j = 0; j < 16; ++j) {
    { int ch = 3*j;      float z = acc[ch]*cp[ch*3]+cp[ch*3+1]; q[j]  = z<0.f ? cp[ch*3+2]*z : z; }
    { int ch = 3*j+1;    float z = acc[ch]*cp[ch*3]+cp[ch*3+1]; k[j]  = z<0.f ? cp[ch*3+2]*z : z; }
    { int ch = 3*j+2;    float z = acc[ch]*cp[ch*3]+cp[ch*3+1]; v[j]  = z<0.f ? cp[ch*3+2]*z : z; }
    { int ch = 48+2*j;   float z = acc[ch]*cp[ch*3]+cp[ch*3+1]; qt[j] = z<0.f ? cp[ch*3+2]*z : z; }
    { int ch = 48+2*j+1; float z = acc[ch]*cp[ch*3]+cp[ch*3+1]; kt[j] = z<0.f ? cp[ch*3+2]*z : z; }
  }
  size_t fo = (((size_t)b*NT + t)*NF + f)*16;   // (B,T,F,16) elements
  size_t to = (((size_t)b*NF + f)*NT + t)*16;   // (B,F,T,16) elements
  uint4* Qf = (uint4*)((unsigned short*)(ws + QF_B) + fo);
  uint4* Kf = (uint4*)((unsigned short*)(ws + KF_B) + fo);
  uint4* Vv = (uint4*)((unsigned short*)(ws + V_B)  + fo);
  uint4* Qt = (uint4*)((unsigned short*)(ws + QT_B) + to);
  uint4* Kt = (uint4*)((unsigned short*)(ws + KT_B) + to);
  Qf[0] = pack8(q);    Qf[1] = pack8(q+8);
  Kf[0] = pack8(k);    Kf[1] = pack8(k+8);
  Vv[0] = pack8(v);    Vv[1] = pack8(v+8);
  Qt[0] = pack8(qt);   Qt[1] = pack8(qt+8);
  Kt[0] = pack8(kt);   Kt[1] = pack8(kt+8);
}

// -------------------- f-attention: per (b,t), 32-row S tiles --------------------
__global__ __launch_bounds__(256) void fattn_k(float* wsf)
{
  __shared__ float    S[32*257];     // 32.9 KB
  __shared__ unsigned Vsb[256*8];    // 8 KB  (V rows, raw bf16 pairs)
  __shared__ float    red[256];
  __shared__ float    rinvs[32];
  char* ws = (char*)wsf;
  const int b = blockIdx.x >> 8;
  const int t = blockIdx.x & 255;
  const int tid = threadIdx.x;
  const size_t base = (((size_t)b*NT + t)*NF)*16;
  const unsigned short* Qh = (const unsigned short*)(ws + QF_B) + base;
  const unsigned short* Kh = (const unsigned short*)(ws + KF_B) + base;
  const uint4* Vb4 = (const uint4*)((const unsigned short*)(ws + V_B) + base);
  unsigned short* Foh = (unsigned short*)(ws + FO_B);
  ((uint4*)Vsb)[tid*2]   = Vb4[tid*2];
  ((uint4*)Vsb)[tid*2+1] = Vb4[tid*2+1];
  float kr[16];
  {
    const uint4* Kb4 = (const uint4*)(Kh + (size_t)tid*16);
    uint4 k0 = Kb4[0], k1 = Kb4[1];
    unsigned kw[8] = {k0.x,k0.y,k0.z,k0.w,k1.x,k1.y,k1.z,k1.w};
#pragma unroll
    for (int j = 0; j < 8; ++j) { kr[2*j] = blo(kw[j]); kr[2*j+1] = bhi(kw[j]); }
  }
  __syncthreads();
  const int r = tid & 31, p = tid >> 5;
  const int prow = tid >> 3, q = tid & 7;
  for (int fb = 0; fb < 8; ++fb) {
    const int f0 = fb*32;
#pragma unroll 4
    for (int fr = 0; fr < 32; ++fr) {
      const unsigned* qw = (const unsigned*)(Qh + (size_t)(f0+fr)*16); // uniform -> s_load
      float s = 0.f;
#pragma unroll
      for (int j = 0; j < 8; ++j) {
        unsigned w = qw[j];
        s += blo(w)*kr[2*j] + bhi(w)*kr[2*j+1];
      }
      S[fr*257 + tid] = s*0.25f;
    }
    __syncthreads();
    float* Srow = S + r*257 + p*32;
    float m = -3.4e38f;
#pragma unroll
    for (int i = 0; i < 32; ++i) m = fmaxf(m, Srow[i]);
    red[tid] = m;
    __syncthreads();
    m = red[r];
#pragma unroll
    for (int k = 1; k < 8; ++k) m = fmaxf(m, red[32*k + r]);
    __syncthreads();
    float sum = 0.f;
#pragma unroll
    for (int i = 0; i < 32; ++i) { float e = __expf(Srow[i]-m); Srow[i] = e; sum += e; }
    red[tid] = sum;
    __syncthreads();
    if (tid < 32) {
      float s2 = red[tid];
#pragma unroll
      for (int k = 1; k < 8; ++k) s2 += red[32*k + tid];
      rinvs[tid] = 1.f / s2;
    }
    __syncthreads();
    const float* Sr = S + prow*257;
    float a0 = 0.f, a1 = 0.f;
#pragma unroll 8
    for (int y = 0; y < 256; ++y) {
      float pw = Sr[y];                       // 8-way broadcast
      unsigned pv = Vsb[y*8 + q];
      a0 += pw*blo(pv); a1 += pw*bhi(pv);
    }
    float ri = rinvs[prow];
    size_t off = (((size_t)b*NF + (f0+prow))*NT + t)*16 + q*2;
    *(unsigned*)(Foh + off) = f2b(a0*ri) | (f2b(a1*ri) << 16);
    __syncthreads();
  }
}

// ---- t-attention (causal) + fused wp conv + BN + PReLU + residual -> Y bf16 ----
__global__ __launch_bounds__(256) void tattn_k(const float* __restrict__ x, float* wsf)
{
  __shared__ float    S[32*257];
  __shared__ unsigned Fsb[256*8];
  __shared__ float    red[256];
  __shared__ float    rinvs[32];
  __shared__ float    Touts[32*17];
  __shared__ float    wpl[1024];
  __shared__ float    bal[128];
  char* ws = (char*)wsf;
  const int b = blockIdx.x >> 8;
  const int f = blockIdx.x & 255;
  const int tid = threadIdx.x;
  const size_t base = (((size_t)b*NF + f)*NT)*16;
  const unsigned short* Qh = (const unsigned short*)(ws + QT_B) + base;
  const unsigned short* Kh = (const unsigned short*)(ws + KT_B) + base;
  const uint4* Fb4 = (const uint4*)((const unsigned short*)(ws + FO_B) + base);
  unsigned short* Yh = (unsigned short*)(ws + Y_B);
  ((uint4*)Fsb)[tid*2]   = Fb4[tid*2];
  ((uint4*)Fsb)[tid*2+1] = Fb4[tid*2+1];
  ((float4*)wpl)[tid] = ((const float4*)(ws + WPS_B))[tid];
  if (tid < 32) ((float4*)bal)[tid] = ((const float4*)(ws + BA_B))[tid];
  float kr[16];
  {
    const uint4* Kb4 = (const uint4*)(Kh + (size_t)tid*16);
    uint4 k0 = Kb4[0], k1 = Kb4[1];
    unsigned kw[8] = {k0.x,k0.y,k0.z,k0.w,k1.x,k1.y,k1.z,k1.w};
#pragma unroll
    for (int j = 0; j < 8; ++j) { kr[2*j] = blo(kw[j]); kr[2*j+1] = bhi(kw[j]); }
  }
  __syncthreads();
  const int r = tid & 31, p = tid >> 5;
  const int prow = tid >> 3, q = tid & 7;
  const int tl = tid & 31, ogrp = tid >> 5;
  for (int tb = 0; tb < 8; ++tb) {
    const int t0 = tb*32;
#pragma unroll 4
    for (int fr = 0; fr < 32; ++fr) {
      const int tq = t0 + fr;
      const unsigned* qw = (const unsigned*)(Qh + (size_t)tq*16);
      float s = 0.f;
#pragma unroll
      for (int j = 0; j < 8; ++j) {
        unsigned w = qw[j];
        s += blo(w)*kr[2*j] + bhi(w)*kr[2*j+1];
      }
      s *= 0.25f;
      if (tid > tq) s = -3.4e38f;            // causal
      S[fr*257 + tid] = s;
    }
    __syncthreads();
    float* Srow = S + r*257 + p*32;
    float m = -3.4e38f;
#pragma unroll
    for (int i = 0; i < 32; ++i) m = fmaxf(m, Srow[i]);
    red[tid] = m;
    __syncthreads();
    m = red[r];
#pragma unroll
    for (int k = 1; k < 8; ++k) m = fmaxf(m, red[32*k + r]);
    __syncthreads();
    float sum = 0.f;
#pragma unroll
    for (int i = 0; i < 32; ++i) { float e = __expf(Srow[i]-m); Srow[i] = e; sum += e; }
    red[tid] = sum;
    __syncthreads();
    if (tid < 32) {
      float s2 = red[tid];
#pragma unroll
      for (int k = 1; k < 8; ++k) s2 += red[32*k + tid];
      rinvs[tid] = 1.f / s2;
    }
    __syncthreads();
    const float* Sr = S + prow*257;
    float a0 = 0.f, a1 = 0.f;
#pragma unroll 8
    for (int y = 0; y < 256; ++y) {
      float pw = Sr[y];
      unsigned pv = Fsb[y*8 + q];
      a0 += pw*blo(pv); a1 += pw*bhi(pv);
    }
    float ri = rinvs[prow];
    Touts[prow*17 + 2*q]     = a0*ri;
    Touts[prow*17 + 2*q + 1] = a1*ri;
    __syncthreads();
    // epilogue: Y[b][o][f][t0+tl] = prelu(bn(wp @ Tout[tl])) + x, stored bf16
    float tr[16];
#pragma unroll
    for (int c = 0; c < 16; ++c) tr[c] = Touts[tl*17 + c];
    const int tg = t0 + tl;
#pragma unroll
    for (int kk = 0; kk < 8; ++kk) {
      const int o = ogrp*8 + kk;
      const float* wr = wpl + o*16;
      float z = 0.f;
#pragma unroll
      for (int c = 0; c < 16; ++c) z += wr[c]*tr[c];
      z += bal[o*2];
      z = z < 0.f ? bal[o*2+1]*z : z;
      size_t oa = (((size_t)b*NC + o)*NF + f)*NT + tg;
      Yh[oa] = (unsigned short)f2b(z + x[oa]);
    }
    __syncthreads();
  }
}

// ---- LN + MLP 64->384->gelu->64 via bf16 MFMA + gamma + residual + transpose-store ----
// block: 256 thr / 4 waves, 64 rows. grid 4096.
__global__ __launch_bounds__(256) void mlp_k(
    const float* __restrict__ x, const float* __restrict__ lnw, const float* __restrict__ lnb,
    const float* __restrict__ b1v, const float* __restrict__ b2v, const float* __restrict__ gm,
    const float* wsf, float* __restrict__ out)
{
  __shared__ __bf16 Asm[64*72];    // LN'd rows, stride 72 (9216 B)
  __shared__ __bf16 Hsm[64*200];   // gelu half (192 ch), stride 200 (25600 B)
  __shared__ float  Osm[64*68];    // out^T [ch][row], stride 68 (17408 B); also LN scratch
  const char* ws = (const char*)wsf;
  const int tid = threadIdx.x;
  const int b   = blockIdx.x >> 10;
  const int r0  = (blockIdx.x & 1023) << 6;
  const unsigned short* Yh = (const unsigned short*)(ws + Y_B) + (size_t)b*BSTRIDE;
  const __bf16* w1p = (const __bf16*)(ws + W1BF_B);
  const __bf16* w2p = (const __bf16*)(ws + W2BF_B);

  // ---------- LN: 4 threads per row ----------
  const int row = tid >> 2, seg = tid & 3;
  float v[16];
  {
    const uint4* src = (const uint4*)(Yh + (size_t)(r0+row)*64 + seg*16);
    uint4 u0 = src[0], u1 = src[1];
    unsigned wwv[8] = {u0.x,u0.y,u0.z,u0.w,u1.x,u1.y,u1.z,u1.w};
#pragma unroll
    for (int j = 0; j < 8; ++j) { v[2*j] = blo(wwv[j]); v[2*j+1] = bhi(wwv[j]); }
  }
  float s1 = 0.f, s2 = 0.f;
#pragma unroll
  for (int j = 0; j < 16; ++j) { s1 += v[j]; s2 += v[j]*v[j]; }
  Osm[row*4 + seg] = s1;
  Osm[256 + row*4 + seg] = s2;
  __syncthreads();
  {
    float sum = Osm[row*4] + Osm[row*4+1] + Osm[row*4+2] + Osm[row*4+3];
    float sq  = Osm[256+row*4] + Osm[256+row*4+1] + Osm[256+row*4+2] + Osm[256+row*4+3];
    float mu  = sum * (1.f/64.f);
    float var = sq * (1.f/64.f) - mu*mu;
    float rstd = rsqrtf(var + 1e-6f);
#pragma unroll
    for (int j = 0; j < 16; ++j) {
      int ch = seg*16 + j;
      Asm[row*72 + ch] = (__bf16)((v[j]-mu)*rstd*lnw[ch] + lnb[ch]);
    }
  }
  __syncthreads();

  // ---------- MFMA phase ----------
  const int w = tid >> 6, lane = tid & 63;
  const int q = lane >> 4, li = lane & 15;
  bf16x8 af[4][2];
#pragma unroll
  for (int mt = 0; mt < 4; ++mt)
#pragma unroll
    for (int kb = 0; kb < 2; ++kb)
      af[mt][kb] = *(const bf16x8*)&Asm[(mt*16 + li)*72 + kb*32 + q*8];

  f32x4 acc2[4];
#pragma unroll
  for (int nt = 0; nt < 4; ++nt) acc2[nt] = (f32x4){0.f,0.f,0.f,0.f};

  for (int half = 0; half < 2; ++half) {
    f32x4 acc[3][4];
#pragma unroll
    for (int a = 0; a < 3; ++a)
#pragma unroll
      for (int m = 0; m < 4; ++m) acc[a][m] = (f32x4){0.f,0.f,0.f,0.f};
#pragma unroll
    for (int nt6 = 0; nt6 < 3; ++nt6) {
      const int nt = half*12 + w*3 + nt6;     // hidden tile
      bf16x8 bf0 = *(const bf16x8*)&w1p[(nt*16 + li)*64 + 0*32 + q*8];
      bf16x8 bf1 = *(const bf16x8*)&w1p[(nt*16 + li)*64 + 1*32 + q*8];
#pragma unroll
      for (int mt = 0; mt < 4; ++mt) {
        acc[nt6][mt] = __builtin_amdgcn_mfma_f32_16x16x32_bf16(af[mt][0], bf0, acc[nt6][mt], 0, 0, 0);
        acc[nt6][mt] = __builtin_amdgcn_mfma_f32_16x16x32_bf16(af[mt][1], bf1, acc[nt6][mt], 0, 0, 0);
      }
    }
    __syncthreads();   // prior-half H reads complete before overwrite
#pragma unroll
    for (int nt6 = 0; nt6 < 3; ++nt6) {
      const int nt  = half*12 + w*3 + nt6;
      const int chg = nt*16 + li;             // global hidden index
      const int chl = chg - half*192;         // local (0..191)
      const float bb = b1v[chg];
#pragma unroll
      for (int mt = 0; mt < 4; ++mt) {
        f32x4 d = acc[nt6][mt];
        const int rl = mt*16 + q*4;
#pragma unroll
        for (int reg = 0; reg < 4; ++reg) {
          float h = d[reg] + bb;
          h = 0.5f*h*(1.f + erff(h*0.70710678118654752f));   // exact gelu
          Hsm[(rl + reg)*200 + chl] = (__bf16)h;
        }
      }
    }
    __syncthreads();
    // GEMM2 partial: rows w*16.., K half
#pragma unroll
    for (int kb2 = 0; kb2 < 6; ++kb2) {
      bf16x8 a2 = *(const bf16x8*)&Hsm[(w*16 + li)*200 + kb2*32 + q*8];
#pragma unroll
      for (int nt = 0; nt < 4; ++nt) {
        bf16x8 b2f = *(const bf16x8*)&w2p[(nt*16 + li)*384 + half*192 + kb2*32 + q*8];
        acc2[nt] = __builtin_amdgcn_mfma_f32_16x16x32_bf16(a2, b2f, acc2[nt], 0, 0, 0);
      }
    }
  }
  __syncthreads();
  // O^T[ch][row] — rows q*4..q*4+3 contiguous -> b128
#pragma unroll
  for (int nt = 0; nt < 4; ++nt)
    *(f32x4*)&Osm[(nt*16 + li)*68 + w*16 + q*4] = acc2[nt];
  __syncthreads();
  // store: wave w -> channels w*16..w*16+15; 256B-coalesced over rows
#pragma unroll 4
  for (int i = 0; i < 16; ++i) {
    const int c = w*16 + i;
    const float g = gm[c], bb2 = b2v[c];
    const size_t addr = (size_t)b*BSTRIDE + (size_t)c*PLANE + r0 + lane;
    out[addr] = x[addr] + g*(Osm[c*68 + lane] + bb2);
  }
}

extern "C" void kernel_launch(void* const* d_in, const int* in_sizes, int n_in,
                              void* d_out, int out_size, void* d_ws, size_t ws_size,
                              hipStream_t stream) {
  const float* x    = (const float*)d_in[0];
  const float* wf   = (const float*)d_in[1];
  const float* f_g  = (const float*)d_in[2];
  const float* f_b  = (const float*)d_in[3];
  const float* f_m  = (const float*)d_in[4];
  const float* f_v  = (const float*)d_in[5];
  const float* f_a  = (const float*)d_in[6];
  const float* wt   = (const float*)d_in[7];
  const float* t_g  = (const float*)d_in[8];
  const float* t_b  = (const float*)d_in[9];
  const float* t_m  = (const float*)d_in[10];
  const float* t_v  = (const float*)d_in[11];
  const float* t_a  = (const float*)d_in[12];
  const float* wp   = (const float*)d_in[13];
  const float* p_g  = (const float*)d_in[14];
  const float* p_b  = (const float*)d_in[15];
  const float* p_m  = (const float*)d_in[16];
  const float* p_v  = (const float*)d_in[17];
  const float* p_a  = (const float*)d_in[18];
  const float* ln_w = (const float*)d_in[19];
  const float* ln_b = (const float*)d_in[20];
  const float* w1   = (const float*)d_in[21];
  const float* b1   = (const float*)d_in[22];
  const float* w2   = (const float*)d_in[23];
  const float* b2   = (const float*)d_in[24];
  const float* gm   = (const float*)d_in[25];
  float* ws  = (float*)d_ws;
  float* out = (float*)d_out;

  setup_k<<<96, 256, 0, stream>>>(wf, f_g, f_b, f_m, f_v, f_a,
                                  wt, t_g, t_b, t_m, t_v, t_a,
                                  wp, p_g, p_b, p_m, p_v, p_a, w1, w2, ws);
  conv_qkv_k<<<NB*NF, 256, 0, stream>>>(x, ws);
  fattn_k   <<<NB*NT, 256, 0, stream>>>(ws);
  tattn_k   <<<NB*NF, 256, 0, stream>>>(x, ws);
  mlp_k     <<<4096,  256, 0, stream>>>(x, ln_w, ln_b, b1, b2, gm, ws, out);
}

// Round 4
// 478.912 us; speedup vs baseline: 3.9188x; 1.5813x over previous
//
#include <hip/hip_runtime.h>
#include <math.h>

// (B,C,F,T) = (4,64,256,256), DC=16
#define NB 4
#define NC 64
#define NF 256
#define NT 256
#define PLANE   65536
#define BSTRIDE 4194304

// ---- workspace layout (BYTE offsets), total 58,851,328 B = 56.1 MB ----
constexpr size_t WT_B   = 0;          // float[5120]   64x80 conv weights (transposed)
constexpr size_t CP_B   = 20480;      // float[240]    80 x {inv,beta,alpha}
constexpr size_t WPS_B  = 21504;      // float[1024]   64x16  wp*inv
constexpr size_t BA_B   = 25600;      // float[128]    64 x {beta,alpha}
constexpr size_t W1BF_B = 26112;      // u16[24576]    w1 bf16 (384x64) row-major
constexpr size_t W2BF_B = 75264;      // u16[24576]    w2 bf16 (64x384) row-major
constexpr size_t QT_B   = 131072;     // bf16[4194304] (B,F,T,16)
constexpr size_t KT_B   = 8519680;    // bf16          (B,F,T,16)
constexpr size_t FO_B   = 16908288;   // bf16          (B,F,T,16)
constexpr size_t QF_B   = 25296896;   // bf16          (B,T,F,16)
constexpr size_t KF_B   = 33685504;   // bf16          (B,T,F,16)
constexpr size_t V_B    = 42074112;   // bf16          (B,T,F,16)
constexpr size_t Y_B    = 25296896;   // bf16[16777216] y_tfsa, overlaps QF/KF/V (dead by then)

typedef __bf16 bf16x8 __attribute__((ext_vector_type(8)));
typedef float  f32x4  __attribute__((ext_vector_type(4)));

__device__ __forceinline__ unsigned f2b(float f) {
  unsigned u = __builtin_bit_cast(unsigned, f);
  return (u + 0x7fffu + ((u >> 16) & 1u)) >> 16;          // RNE
}
__device__ __forceinline__ float blo(unsigned u) { return __builtin_bit_cast(float, u << 16); }
__device__ __forceinline__ float bhi(unsigned u) { return __builtin_bit_cast(float, u & 0xffff0000u); }
__device__ __forceinline__ uint4 pack8(const float* s) {
  uint4 r;
  r.x = f2b(s[0]) | (f2b(s[1]) << 16);
  r.y = f2b(s[2]) | (f2b(s[3]) << 16);
  r.z = f2b(s[4]) | (f2b(s[5]) << 16);
  r.w = f2b(s[6]) | (f2b(s[7]) << 16);
  return r;
}
__device__ __forceinline__ bf16x8 bzero8() {
  bf16x8 z;
#pragma unroll
  for (int j = 0; j < 8; ++j) z[j] = (__bf16)0.f;
  return z;
}

// ---------------- setup: folded BN params + weight transposes ----------------
__global__ __launch_bounds__(256) void setup_k(
    const float* __restrict__ wf, const float* __restrict__ fg, const float* __restrict__ fb,
    const float* __restrict__ fm, const float* __restrict__ fv, const float* __restrict__ fa,
    const float* __restrict__ wt, const float* __restrict__ tg, const float* __restrict__ tb,
    const float* __restrict__ tm, const float* __restrict__ tv, const float* __restrict__ ta,
    const float* __restrict__ wp, const float* __restrict__ pg, const float* __restrict__ pb,
    const float* __restrict__ pm, const float* __restrict__ pv, const float* __restrict__ pa,
    const float* __restrict__ w1, const float* __restrict__ w2, float* __restrict__ wsf)
{
  char* ws = (char*)wsf;
  int tid  = blockIdx.x * blockDim.x + threadIdx.x;
  int nthr = gridDim.x * blockDim.x;
  float* WT  = (float*)(ws + WT_B);
  float* cp  = (float*)(ws + CP_B);
  float* wps = (float*)(ws + WPS_B);
  float* ba  = (float*)(ws + BA_B);
  unsigned short* w1b = (unsigned short*)(ws + W1BF_B);
  unsigned short* w2b = (unsigned short*)(ws + W2BF_B);
  for (int i = tid; i < 64*80; i += nthr) {
    int c = i / 80, o = i % 80;
    WT[i] = (o < 48) ? wf[o*64 + c] : wt[(o-48)*64 + c];
  }
  for (int o = tid; o < 80; o += nthr) {
    float g, bb, m, v, a;
    if (o < 48) { g = fg[o]; bb = fb[o]; m = fm[o]; v = fv[o]; a = fa[o]; }
    else { int j = o - 48; g = tg[j]; bb = tb[j]; m = tm[j]; v = tv[j]; a = ta[j]; }
    float inv = g * rsqrtf(v + 1e-5f);
    cp[o*3+0] = inv; cp[o*3+1] = bb - m*inv; cp[o*3+2] = a;
  }
  for (int i = tid; i < 1024; i += nthr) {
    int o = i >> 4;
    float inv = pg[o] * rsqrtf(pv[o] + 1e-5f);
    wps[i] = wp[i] * inv;
  }
  for (int o = tid; o < 64; o += nthr) {
    float inv = pg[o] * rsqrtf(pv[o] + 1e-5f);
    ba[o*2+0] = pb[o] - pm[o]*inv; ba[o*2+1] = pa[o];
  }
  for (int i = tid; i < 384*64; i += nthr) {
    w1b[i] = (unsigned short)f2b(w1[i]);   // w1b[g][c], 384x64
    w2b[i] = (unsigned short)f2b(w2[i]);   // w2b[c][g], 64x384
  }
}

// -------- fused conv1x1(wf|wt) + BN + PReLU, deinterleave, store bf16 --------
__global__ __launch_bounds__(256) void conv_qkv_k(const float* __restrict__ x, float* wsf)
{
  char* ws = (char*)wsf;
  const int b = blockIdx.x >> 8;
  const int f = blockIdx.x & 255;
  const int t = threadIdx.x;
  const float* WT = (const float*)(ws + WT_B);   // wave-uniform rows -> s_load
  const float* cp = (const float*)(ws + CP_B);
  const float* xb = x + (size_t)b*BSTRIDE + (size_t)f*NT + t;
  float acc[80];
#pragma unroll
  for (int o = 0; o < 80; ++o) acc[o] = 0.f;
  for (int c = 0; c < 64; ++c) {
    float xc = xb[(size_t)c*PLANE];
    const float* w = WT + c*80;
#pragma unroll
    for (int o = 0; o < 80; ++o) acc[o] += w[o]*xc;
  }
  float q[16], k[16], v[16], qt[16], kt[16];
#pragma unroll
  for (int j = 0; j < 16; ++j) {
    { int ch = 3*j;      float z = acc[ch]*cp[ch*3]+cp[ch*3+1]; q[j]  = z<0.f ? cp[ch*3+2]*z : z; }
    { int ch = 3*j+1;    float z = acc[ch]*cp[ch*3]+cp[ch*3+1]; k[j]  = z<0.f ? cp[ch*3+2]*z : z; }
    { int ch = 3*j+2;    float z = acc[ch]*cp[ch*3]+cp[ch*3+1]; v[j]  = z<0.f ? cp[ch*3+2]*z : z; }
    { int ch = 48+2*j;   float z = acc[ch]*cp[ch*3]+cp[ch*3+1]; qt[j] = z<0.f ? cp[ch*3+2]*z : z; }
    { int ch = 48+2*j+1; float z = acc[ch]*cp[ch*3]+cp[ch*3+1]; kt[j] = z<0.f ? cp[ch*3+2]*z : z; }
  }
  size_t fo = (((size_t)b*NT + t)*NF + f)*16;   // (B,T,F,16) elements
  size_t to = (((size_t)b*NF + f)*NT + t)*16;   // (B,F,T,16) elements
  uint4* Qf = (uint4*)((unsigned short*)(ws + QF_B) + fo);
  uint4* Kf = (uint4*)((unsigned short*)(ws + KF_B) + fo);
  uint4* Vv = (uint4*)((unsigned short*)(ws + V_B)  + fo);
  uint4* Qt = (uint4*)((unsigned short*)(ws + QT_B) + to);
  uint4* Kt = (uint4*)((unsigned short*)(ws + KT_B) + to);
  Qf[0] = pack8(q);    Qf[1] = pack8(q+8);
  Kf[0] = pack8(k);    Kf[1] = pack8(k+8);
  Vv[0] = pack8(v);    Vv[1] = pack8(v+8);
  Qt[0] = pack8(qt);   Qt[1] = pack8(qt+8);
  Kt[0] = pack8(kt);   Kt[1] = pack8(kt+8);
}

// =================== MFMA attention ===================
// Per block: one (b, pivot). Q,K,V panels are 256x16 bf16, rows contiguous.
// S = Q·K^T via 16x16x32 MFMA (k>=16 zero-padded), softmax per 32-row strip,
// O = P·V via 16x16x32 with V^T staged in LDS. P stored unnormalized; 1/l at
// epilogue. Layouts (guide-verified): A[m=lane&15][k=quad*8+j],
// B[k=quad*8+j][n=lane&15], C/D col=lane&15,row=quad*4+reg.

// -------------------- f-attention --------------------
__global__ __launch_bounds__(256) void fattn_k(float* wsf)
{
  __shared__ char smem[62976];
  float*  S    = (float*)smem;                           // [32][260] fp32
  unsigned short* Pl = (unsigned short*)(smem + 33280);  // [32][264] bf16
  unsigned short* Vt = (unsigned short*)(smem + 50176);  // [16][264] bf16 (V^T)
  float*  Ored = (float*)(smem + 58624);                 // [2][32][17] fp32
  char* ws = (char*)wsf;
  const int b = blockIdx.x >> 8;
  const int t = blockIdx.x & 255;
  const int tid = threadIdx.x;
  const int w = tid >> 6, lane = tid & 63;
  const int li = lane & 15, quad = lane >> 4;
  const size_t base = (((size_t)b*NT + t)*NF)*16;
  const __bf16* Qh = (const __bf16*)((const unsigned short*)(ws + QF_B) + base);
  const __bf16* Kh = (const __bf16*)((const unsigned short*)(ws + KF_B) + base);
  const unsigned short* Vh = (const unsigned short*)(ws + V_B) + base;
  unsigned short* Foh = (unsigned short*)(ws + FO_B);

  // stage V^T
  {
    const uint4* vr = (const uint4*)(Vh + (size_t)tid*16);
    uint4 v0 = vr[0], v1 = vr[1];
    unsigned vw[8] = {v0.x,v0.y,v0.z,v0.w,v1.x,v1.y,v1.z,v1.w};
#pragma unroll
    for (int j = 0; j < 8; ++j) {
      Vt[(2*j)*264 + tid]   = (unsigned short)(vw[j] & 0xffffu);
      Vt[(2*j+1)*264 + tid] = (unsigned short)(vw[j] >> 16);
    }
  }
  // K B-frags (wave w: n-tiles 2w, 2w+1); k>=16 zero
  bf16x8 bk[2];
#pragma unroll
  for (int i = 0; i < 2; ++i) {
    bk[i] = bzero8();
    if (quad < 2)
      bk[i] = *(const bf16x8*)(Kh + ((2*w+i)*16 + li)*16 + quad*8);
  }
  __syncthreads();
  // V B-frags (wave: wm=w&1 m-tile, wk=w>>1 k-half)
  const int wm = w & 1, wk = w >> 1;
  bf16x8 bv[4];
#pragma unroll
  for (int s = 0; s < 4; ++s)
    bv[s] = *(const bf16x8*)((const __bf16*)Vt + li*264 + (wk*4+s)*32 + quad*8);

  const int r = tid >> 3, seg = tid & 7;   // softmax/epilogue mapping

  for (int st = 0; st < 8; ++st) {
    const int m0 = st*32;
    // ---- QK: wave w computes m-tiles {0,1} x n-tiles {2w,2w+1} ----
    bf16x8 aq[2];
#pragma unroll
    for (int mt = 0; mt < 2; ++mt) {
      aq[mt] = bzero8();
      if (quad < 2)
        aq[mt] = *(const bf16x8*)(Qh + (m0 + mt*16 + li)*16 + quad*8);
    }
#pragma unroll
    for (int i = 0; i < 2; ++i) {
      const int nt = 2*w + i;
#pragma unroll
      for (int mt = 0; mt < 2; ++mt) {
        f32x4 sa = {0.f,0.f,0.f,0.f};
        sa = __builtin_amdgcn_mfma_f32_16x16x32_bf16(aq[mt], bk[i], sa, 0, 0, 0);
#pragma unroll
        for (int reg = 0; reg < 4; ++reg)
          S[(mt*16 + quad*4 + reg)*260 + nt*16 + li] = sa[reg]*0.25f;
      }
    }
    __syncthreads();
    // ---- softmax (thread r in [0,32), seg in [0,8)) ----
    float vals[32];
    const float* Srow = S + r*260 + seg*32;
#pragma unroll
    for (int i = 0; i < 8; ++i) {
      f32x4 tmp = *(const f32x4*)(Srow + 4*i);
      vals[4*i]=tmp[0]; vals[4*i+1]=tmp[1]; vals[4*i+2]=tmp[2]; vals[4*i+3]=tmp[3];
    }
    float mx = vals[0];
#pragma unroll
    for (int i = 1; i < 32; ++i) mx = fmaxf(mx, vals[i]);
    mx = fmaxf(mx, __shfl_xor(mx, 1));
    mx = fmaxf(mx, __shfl_xor(mx, 2));
    mx = fmaxf(mx, __shfl_xor(mx, 4));
    float sum = 0.f;
#pragma unroll
    for (int i = 0; i < 32; ++i) { float e = __expf(vals[i]-mx); vals[i]=e; sum += e; }
    sum += __shfl_xor(sum, 1);
    sum += __shfl_xor(sum, 2);
    sum += __shfl_xor(sum, 4);
    const float rinv = 1.f / sum;
    unsigned* Pw = (unsigned*)Pl + r*132 + seg*16;
#pragma unroll
    for (int i = 0; i < 16; ++i)
      Pw[i] = f2b(vals[2*i]) | (f2b(vals[2*i+1]) << 16);
    __syncthreads();
    // ---- PV: wave (wm, wk): m-tile wm, k-steps wk*4..wk*4+3 ----
    f32x4 aco = {0.f,0.f,0.f,0.f};
#pragma unroll
    for (int s = 0; s < 4; ++s) {
      bf16x8 ap = *(const bf16x8*)((const __bf16*)Pl + (wm*16 + li)*264 + (wk*4+s)*32 + quad*8);
      aco = __builtin_amdgcn_mfma_f32_16x16x32_bf16(ap, bv[s], aco, 0, 0, 0);
    }
#pragma unroll
    for (int reg = 0; reg < 4; ++reg)
      Ored[wk*544 + (wm*16 + quad*4 + reg)*17 + li] = aco[reg];
    __syncthreads();
    // ---- epilogue: thread (m=r, cp=seg); rinv is this thread's row ----
    {
      float o0 = (Ored[r*17 + 2*seg]     + Ored[544 + r*17 + 2*seg])     * rinv;
      float o1 = (Ored[r*17 + 2*seg + 1] + Ored[544 + r*17 + 2*seg + 1]) * rinv;
      unsigned pk = f2b(o0) | (f2b(o1) << 16);
      *(unsigned*)(Foh + ((((size_t)b*NF + (m0+r))*NT + t)*16 + 2*seg)) = pk;
    }
    __syncthreads();
  }
}

// ---- t-attention (causal) + fused wp conv + BN + PReLU + residual -> Y bf16 ----
__global__ __launch_bounds__(256) void tattn_k(const float* __restrict__ x, float* wsf)
{
  __shared__ char smem[65280];
  float*  S    = (float*)smem;                           // [32][260]
  unsigned short* Pl = (unsigned short*)(smem + 33280);  // [32][264]
  unsigned short* Ft = (unsigned short*)(smem + 50176);  // [16][264] (f_out^T)
  float*  Ored = (float*)(smem + 58624);                 // [2][32][17]; [.][r][16] = rinv
  unsigned* wplw = (unsigned*)(smem + 62976);            // [512] bf16 pairs of wp*inv
  unsigned* balw = (unsigned*)(smem + 65024);            // [64]  {beta,alpha} bf16 pairs
  char* ws = (char*)wsf;
  const int b = blockIdx.x >> 8;
  const int f = blockIdx.x & 255;
  const int tid = threadIdx.x;
  const int w = tid >> 6, lane = tid & 63;
  const int li = lane & 15, quad = lane >> 4;
  const size_t base = (((size_t)b*NF + f)*NT)*16;
  const __bf16* Qh = (const __bf16*)((const unsigned short*)(ws + QT_B) + base);
  const __bf16* Kh = (const __bf16*)((const unsigned short*)(ws + KT_B) + base);
  const unsigned short* Fh = (const unsigned short*)(ws + FO_B) + base;
  unsigned short* Yh = (unsigned short*)(ws + Y_B);

  // stage f_out^T + wp/bal tables
  {
    const uint4* vr = (const uint4*)(Fh + (size_t)tid*16);
    uint4 v0 = vr[0], v1 = vr[1];
    unsigned vw[8] = {v0.x,v0.y,v0.z,v0.w,v1.x,v1.y,v1.z,v1.w};
#pragma unroll
    for (int j = 0; j < 8; ++j) {
      Ft[(2*j)*264 + tid]   = (unsigned short)(vw[j] & 0xffffu);
      Ft[(2*j+1)*264 + tid] = (unsigned short)(vw[j] >> 16);
    }
    const float* wps = (const float*)(ws + WPS_B);
    const float* ba  = (const float*)(ws + BA_B);
#pragma unroll
    for (int i = tid; i < 512; i += 256)
      wplw[i] = f2b(wps[2*i]) | (f2b(wps[2*i+1]) << 16);
    if (tid < 64)
      balw[tid] = f2b(ba[2*tid]) | (f2b(ba[2*tid+1]) << 16);
  }
  bf16x8 bk[2];
#pragma unroll
  for (int i = 0; i < 2; ++i) {
    bk[i] = bzero8();
    if (quad < 2)
      bk[i] = *(const bf16x8*)(Kh + ((2*w+i)*16 + li)*16 + quad*8);
  }
  __syncthreads();
  const int wm = w & 1, wk = w >> 1;
  bf16x8 bv[4];
#pragma unroll
  for (int s = 0; s < 4; ++s)
    bv[s] = *(const bf16x8*)((const __bf16*)Ft + li*264 + (wk*4+s)*32 + quad*8);

  const int r = tid >> 3, seg = tid & 7;
  const int tl = tid & 31, ogrp = tid >> 5;

  for (int st = 0; st < 8; ++st) {
    const int m0 = st*32;
    // ---- QK (triangular: tile computed iff n-tile <= 2*st + mt) ----
    bf16x8 aq[2];
#pragma unroll
    for (int mt = 0; mt < 2; ++mt) {
      aq[mt] = bzero8();
      if (quad < 2)
        aq[mt] = *(const bf16x8*)(Qh + (m0 + mt*16 + li)*16 + quad*8);
    }
#pragma unroll
    for (int i = 0; i < 2; ++i) {
      const int nt = 2*w + i;
#pragma unroll
      for (int mt = 0; mt < 2; ++mt) {
        if (nt <= 2*st + mt) {
          f32x4 sa = {0.f,0.f,0.f,0.f};
          sa = __builtin_amdgcn_mfma_f32_16x16x32_bf16(aq[mt], bk[i], sa, 0, 0, 0);
#pragma unroll
          for (int reg = 0; reg < 4; ++reg)
            S[(mt*16 + quad*4 + reg)*260 + nt*16 + li] = sa[reg]*0.25f;
        }
      }
    }
    __syncthreads();
    // ---- softmax with causal mask: row tq = m0+r, cols [seg*32, seg*32+32) ----
    float vals[32];
    const float* Srow = S + r*260 + seg*32;
#pragma unroll
    for (int i = 0; i < 8; ++i) {
      f32x4 tmp = *(const f32x4*)(Srow + 4*i);
      vals[4*i]=tmp[0]; vals[4*i+1]=tmp[1]; vals[4*i+2]=tmp[2]; vals[4*i+3]=tmp[3];
    }
    const int lim = (m0 + r) - seg*32 + 1;   // #valid cols in segment
#pragma unroll
    for (int i = 0; i < 32; ++i)
      if (i >= lim) vals[i] = -3.4e38f;
    float mx = vals[0];
#pragma unroll
    for (int i = 1; i < 32; ++i) mx = fmaxf(mx, vals[i]);
    mx = fmaxf(mx, __shfl_xor(mx, 1));
    mx = fmaxf(mx, __shfl_xor(mx, 2));
    mx = fmaxf(mx, __shfl_xor(mx, 4));
    float sum = 0.f;
#pragma unroll
    for (int i = 0; i < 32; ++i) { float e = __expf(vals[i]-mx); vals[i]=e; sum += e; }
    sum += __shfl_xor(sum, 1);
    sum += __shfl_xor(sum, 2);
    sum += __shfl_xor(sum, 4);
    if (seg == 0) Ored[r*17 + 16] = 1.f / sum;   // rinv slot (pad word)
    unsigned* Pw = (unsigned*)Pl + r*132 + seg*16;
#pragma unroll
    for (int i = 0; i < 16; ++i)
      Pw[i] = f2b(vals[2*i]) | (f2b(vals[2*i+1]) << 16);
    __syncthreads();
    // ---- PV (k-steps with any valid col: wk*4+s <= st) ----
    f32x4 aco = {0.f,0.f,0.f,0.f};
#pragma unroll
    for (int s = 0; s < 4; ++s) {
      if (wk*4 + s <= st) {
        bf16x8 ap = *(const bf16x8*)((const __bf16*)Pl + (wm*16 + li)*264 + (wk*4+s)*32 + quad*8);
        aco = __builtin_amdgcn_mfma_f32_16x16x32_bf16(ap, bv[s], aco, 0, 0, 0);
      }
    }
#pragma unroll
    for (int reg = 0; reg < 4; ++reg)
      Ored[wk*544 + (wm*16 + quad*4 + reg)*17 + li] = aco[reg];
    __syncthreads();
    // ---- epilogue: thread (tl, ogrp): t-row tl, channels ogrp*8..+7 ----
    {
      const float rinv = Ored[tl*17 + 16];
      float tr[16];
#pragma unroll
      for (int c = 0; c < 16; ++c)
        tr[c] = (Ored[tl*17 + c] + Ored[544 + tl*17 + c]) * rinv;
      const int tg = m0 + tl;
#pragma unroll
      for (int kk = 0; kk < 8; ++kk) {
        const int o = ogrp*8 + kk;
        const unsigned* wr = wplw + o*8;
        float z = 0.f;
#pragma unroll
        for (int j = 0; j < 8; ++j) {
          unsigned wv = wr[j];
          z += blo(wv)*tr[2*j] + bhi(wv)*tr[2*j+1];
        }
        unsigned bw = balw[o];
        z += blo(bw);
        z = z < 0.f ? bhi(bw)*z : z;
        size_t oa = (((size_t)b*NC + o)*NF + f)*NT + tg;
        Yh[oa] = (unsigned short)f2b(z + x[oa]);
      }
    }
    __syncthreads();
  }
}

// ---- LN + MLP 64->384->gelu->64 via bf16 MFMA + gamma + residual + transpose-store ----
__global__ __launch_bounds__(256) void mlp_k(
    const float* __restrict__ x, const float* __restrict__ lnw, const float* __restrict__ lnb,
    const float* __restrict__ b1v, const float* __restrict__ b2v, const float* __restrict__ gm,
    const float* wsf, float* __restrict__ out)
{
  __shared__ __bf16 Asm[64*72];    // LN'd rows, stride 72 (9216 B)
  __shared__ __bf16 Hsm[64*200];   // gelu half (192 ch), stride 200 (25600 B)
  __shared__ float  Osm[64*68];    // out^T [ch][row], stride 68 (17408 B); also LN scratch
  const char* ws = (const char*)wsf;
  const int tid = threadIdx.x;
  const int b   = blockIdx.x >> 10;
  const int r0  = (blockIdx.x & 1023) << 6;
  const unsigned short* Yh = (const unsigned short*)(ws + Y_B) + (size_t)b*BSTRIDE;
  const __bf16* w1p = (const __bf16*)(ws + W1BF_B);
  const __bf16* w2p = (const __bf16*)(ws + W2BF_B);

  // ---------- LN: 4 threads per row ----------
  const int row = tid >> 2, seg = tid & 3;
  float v[16];
  {
    const uint4* src = (const uint4*)(Yh + (size_t)(r0+row)*64 + seg*16);
    uint4 u0 = src[0], u1 = src[1];
    unsigned wwv[8] = {u0.x,u0.y,u0.z,u0.w,u1.x,u1.y,u1.z,u1.w};
#pragma unroll
    for (int j = 0; j < 8; ++j) { v[2*j] = blo(wwv[j]); v[2*j+1] = bhi(wwv[j]); }
  }
  float s1 = 0.f, s2 = 0.f;
#pragma unroll
  for (int j = 0; j < 16; ++j) { s1 += v[j]; s2 += v[j]*v[j]; }
  Osm[row*4 + seg] = s1;
  Osm[256 + row*4 + seg] = s2;
  __syncthreads();
  {
    float sum = Osm[row*4] + Osm[row*4+1] + Osm[row*4+2] + Osm[row*4+3];
    float sq  = Osm[256+row*4] + Osm[256+row*4+1] + Osm[256+row*4+2] + Osm[256+row*4+3];
    float mu  = sum * (1.f/64.f);
    float var = sq * (1.f/64.f) - mu*mu;
    float rstd = rsqrtf(var + 1e-6f);
#pragma unroll
    for (int j = 0; j < 16; ++j) {
      int ch = seg*16 + j;
      Asm[row*72 + ch] = (__bf16)((v[j]-mu)*rstd*lnw[ch] + lnb[ch]);
    }
  }
  __syncthreads();

  // ---------- MFMA phase ----------
  const int w = tid >> 6, lane = tid & 63;
  const int q = lane >> 4, li = lane & 15;
  bf16x8 af[4][2];
#pragma unroll
  for (int mt = 0; mt < 4; ++mt)
#pragma unroll
    for (int kb = 0; kb < 2; ++kb)
      af[mt][kb] = *(const bf16x8*)&Asm[(mt*16 + li)*72 + kb*32 + q*8];

  f32x4 acc2[4];
#pragma unroll
  for (int nt = 0; nt < 4; ++nt) acc2[nt] = (f32x4){0.f,0.f,0.f,0.f};

  for (int half = 0; half < 2; ++half) {
    f32x4 acc[3][4];
#pragma unroll
    for (int a = 0; a < 3; ++a)
#pragma unroll
      for (int m = 0; m < 4; ++m) acc[a][m] = (f32x4){0.f,0.f,0.f,0.f};
#pragma unroll
    for (int nt6 = 0; nt6 < 3; ++nt6) {
      const int nt = half*12 + w*3 + nt6;     // hidden tile
      bf16x8 bf0 = *(const bf16x8*)&w1p[(nt*16 + li)*64 + 0*32 + q*8];
      bf16x8 bf1 = *(const bf16x8*)&w1p[(nt*16 + li)*64 + 1*32 + q*8];
#pragma unroll
      for (int mt = 0; mt < 4; ++mt) {
        acc[nt6][mt] = __builtin_amdgcn_mfma_f32_16x16x32_bf16(af[mt][0], bf0, acc[nt6][mt], 0, 0, 0);
        acc[nt6][mt] = __builtin_amdgcn_mfma_f32_16x16x32_bf16(af[mt][1], bf1, acc[nt6][mt], 0, 0, 0);
      }
    }
    __syncthreads();   // prior-half H reads complete before overwrite
#pragma unroll
    for (int nt6 = 0; nt6 < 3; ++nt6) {
      const int nt  = half*12 + w*3 + nt6;
      const int chg = nt*16 + li;             // global hidden index
      const int chl = chg - half*192;         // local (0..191)
      const float bb = b1v[chg];
#pragma unroll
      for (int mt = 0; mt < 4; ++mt) {
        f32x4 d = acc[nt6][mt];
        const int rl = mt*16 + q*4;
#pragma unroll
        for (int reg = 0; reg < 4; ++reg) {
          float h = d[reg] + bb;
          h = 0.5f*h*(1.f + erff(h*0.70710678118654752f));   // exact gelu
          Hsm[(rl + reg)*200 + chl] = (__bf16)h;
        }
      }
    }
    __syncthreads();
    // GEMM2 partial: rows w*16.., K half
#pragma unroll
    for (int kb2 = 0; kb2 < 6; ++kb2) {
      bf16x8 a2 = *(const bf16x8*)&Hsm[(w*16 + li)*200 + kb2*32 + q*8];
#pragma unroll
      for (int nt = 0; nt < 4; ++nt) {
        bf16x8 b2f = *(const bf16x8*)&w2p[(nt*16 + li)*384 + half*192 + kb2*32 + q*8];
        acc2[nt] = __builtin_amdgcn_mfma_f32_16x16x32_bf16(a2, b2f, acc2[nt], 0, 0, 0);
      }
    }
  }
  __syncthreads();
  // O^T[ch][row] — rows q*4..q*4+3 contiguous -> b128
#pragma unroll
  for (int nt = 0; nt < 4; ++nt)
    *(f32x4*)&Osm[(nt*16 + li)*68 + w*16 + q*4] = acc2[nt];
  __syncthreads();
  // store: wave w -> channels w*16..w*16+15; 256B-coalesced over rows
#pragma unroll 4
  for (int i = 0; i < 16; ++i) {
    const int c = w*16 + i;
    const float g = gm[c], bb2 = b2v[c];
    const size_t addr = (size_t)b*BSTRIDE + (size_t)c*PLANE + r0 + lane;
    out[addr] = x[addr] + g*(Osm[c*68 + lane] + bb2);
  }
}

extern "C" void kernel_launch(void* const* d_in, const int* in_sizes, int n_in,
                              void* d_out, int out_size, void* d_ws, size_t ws_size,
                              hipStream_t stream) {
  const float* x    = (const float*)d_in[0];
  const float* wf   = (const float*)d_in[1];
  const float* f_g  = (const float*)d_in[2];
  const float* f_b  = (const float*)d_in[3];
  const float* f_m  = (const float*)d_in[4];
  const float* f_v  = (const float*)d_in[5];
  const float* f_a  = (const float*)d_in[6];
  const float* wt   = (const float*)d_in[7];
  const float* t_g  = (const float*)d_in[8];
  const float* t_b  = (const float*)d_in[9];
  const float* t_m  = (const float*)d_in[10];
  const float* t_v  = (const float*)d_in[11];
  const float* t_a  = (const float*)d_in[12];
  const float* wp   = (const float*)d_in[13];
  const float* p_g  = (const float*)d_in[14];
  const float* p_b  = (const float*)d_in[15];
  const float* p_m  = (const float*)d_in[16];
  const float* p_v  = (const float*)d_in[17];
  const float* p_a  = (const float*)d_in[18];
  const float* ln_w = (const float*)d_in[19];
  const float* ln_b = (const float*)d_in[20];
  const float* w1   = (const float*)d_in[21];
  const float* b1   = (const float*)d_in[22];
  const float* w2   = (const float*)d_in[23];
  const float* b2   = (const float*)d_in[24];
  const float* gm   = (const float*)d_in[25];
  float* ws  = (float*)d_ws;
  float* out = (float*)d_out;

  setup_k<<<96, 256, 0, stream>>>(wf, f_g, f_b, f_m, f_v, f_a,
                                  wt, t_g, t_b, t_m, t_v, t_a,
                                  wp, p_g, p_b, p_m, p_v, p_a, w1, w2, ws);
  conv_qkv_k<<<NB*NF, 256, 0, stream>>>(x, ws);
  fattn_k   <<<NB*NT, 256, 0, stream>>>(ws);
  tattn_k   <<<NB*NF, 256, 0, stream>>>(x, ws);
  mlp_k     <<<4096,  256, 0, stream>>>(x, ln_w, ln_b, b1, b2, gm, ws, out);
}